// Round 3
// baseline (903.141 us; speedup 1.0000x reference)
//
#include <hip/hip_runtime.h>
#include <math.h>

#define NLVL 16
#define MAXP (1u << 19)

typedef float f32x4 __attribute__((ext_vector_type(4)));

struct LP {
    float        scale[NLVL];
    unsigned int res[NLVL];
    unsigned int hsize[NLVL];
    unsigned int offset[NLVL];
    unsigned int hashed[NLVL];
};

// 4 threads per point, 4 consecutive levels per thread.
// Thread g: point i = g>>2, level group lg = g&3 (levels lg*4 .. lg*4+3).
// Output for thread g is 8 contiguous floats at out + g*8 -> fully coalesced.
__global__ __launch_bounds__(256, 4) void grid_enc_kernel(
    const float* __restrict__ in, const float* __restrict__ emb,
    float* __restrict__ out, int n, LP lp)
{
    __shared__ float        s_scale[NLVL];
    __shared__ unsigned int s_res[NLVL], s_hs[NLVL], s_off[NLVL], s_hashed[NLVL];
    if (threadIdx.x == 0) {
        // compile-time indices only (no runtime-indexed kernarg access)
        #pragma unroll
        for (int j = 0; j < NLVL; ++j) {
            s_scale[j]  = lp.scale[j];
            s_res[j]    = lp.res[j];
            s_hs[j]     = lp.hsize[j];
            s_off[j]    = lp.offset[j];
            s_hashed[j] = lp.hashed[j];
        }
    }
    __syncthreads();

    const int g  = blockIdx.x * blockDim.x + threadIdx.x;
    const int i  = g >> 2;
    const int lg = g & 3;
    if (i >= n) return;

    const float x = (in[3 * i + 0] + 1.0f) * 0.5f;
    const float y = (in[3 * i + 1] + 1.0f) * 0.5f;
    const float z = (in[3 * i + 2] + 1.0f) * 0.5f;

    float fout[8];

    #pragma unroll
    for (int j = 0; j < 4; ++j) {
        const int l = (lg << 2) + j;
        const float s  = s_scale[l];
        const float px = x * s, py = y * s, pz = z * s;
        const float gx = floorf(px), gy = floorf(py), gz = floorf(pz);
        const float wx = px - gx, wy = py - gy, wz = pz - gz;
        const unsigned int bx = (unsigned int)(int)gx;
        const unsigned int by = (unsigned int)(int)gy;
        const unsigned int bz = (unsigned int)(int)gz;
        const unsigned int r   = s_res[l];
        const unsigned int hs  = s_hs[l];
        const unsigned int off = s_off[l];
        const bool hashed = (s_hashed[l] != 0u);

        // hash terms (uint32 wrap; adds distribute over mod 2^32)
        const unsigned int hy0 = by * 2654435761u;
        const unsigned int hy1 = hy0 + 2654435761u;
        const unsigned int hz0 = bz * 805459861u;
        const unsigned int hz1 = hz0 + 805459861u;
        // dense terms
        const unsigned int dy0 = by * r;
        const unsigned int dy1 = dy0 + r;
        const unsigned int dz0 = bz * r * r;
        const unsigned int dz1 = dz0 + r * r;

        float a0 = 0.0f, a1 = 0.0f;
        #pragma unroll
        for (int c = 0; c < 8; ++c) {
            const unsigned int dx = c & 1u, dyb = (c >> 1) & 1u, dzb = (c >> 2) & 1u;
            const unsigned int ix = bx + dx;
            unsigned int idx;
            if (hashed) {
                idx = (ix ^ (dyb ? hy1 : hy0) ^ (dzb ? hz1 : hz0)) & (hs - 1u);
            } else {
                // idx < 2*hs provably -> one conditional subtract == `% hsize`
                idx = ix + (dyb ? dy1 : dy0) + (dzb ? dz1 : dz0);
                if (idx >= hs) idx -= hs;
            }
            const float2 f = *(const float2*)(emb + (size_t)(off + idx) * 2u);
            const float w = (dx  ? wx : 1.0f - wx) *
                            (dyb ? wy : 1.0f - wy) *
                            (dzb ? wz : 1.0f - wz);
            a0 = fmaf(w, f.x, a0);
            a1 = fmaf(w, f.y, a1);
        }
        fout[2 * j + 0] = a0;
        fout[2 * j + 1] = a1;
    }

    // streaming output: nontemporal so the 128 MB write doesn't evict the
    // 48.8 MB embedding table from L2 (native clang vector type — HIP float4
    // is a class and is rejected by the builtin)
    f32x4 v0 = { fout[0], fout[1], fout[2], fout[3] };
    f32x4 v1 = { fout[4], fout[5], fout[6], fout[7] };
    f32x4* o4 = (f32x4*)(out + (size_t)g * 8);
    __builtin_nontemporal_store(v0, o4);
    __builtin_nontemporal_store(v1, o4 + 1);
}

extern "C" void kernel_launch(void* const* d_in, const int* in_sizes, int n_in,
                              void* d_out, int out_size, void* d_ws, size_t ws_size,
                              hipStream_t stream)
{
    const float* in  = (const float*)d_in[0];
    const float* emb = (const float*)d_in[1];
    float* out = (float*)d_out;
    const int n = in_sizes[0] / 3;

    // Per-level params, f64 exactly as the Python reference.
    LP lp;
    unsigned int offset = 0;
    const double log2s = log2(1.3819);
    for (int l = 0; l < NLVL; ++l) {
        const double scale = pow(2.0, (double)l * log2s) * 16.0 - 1.0;
        const int res = (int)ceil(scale) + 1;
        const long long r3 = (long long)res * res * res;
        const bool dense = (r3 <= (long long)MAXP);
        long long pil = dense ? r3 : (long long)MAXP;
        pil = (pil + 7) / 8 * 8;
        lp.scale[l]  = (float)scale;
        lp.res[l]    = (unsigned int)res;
        lp.hsize[l]  = (unsigned int)pil;
        lp.offset[l] = offset;
        lp.hashed[l] = dense ? 0u : 1u;
        offset += (unsigned int)pil;
    }

    const int block = 256;
    const long long threads = (long long)n * 4;
    const int grid = (int)((threads + block - 1) / block);
    grid_enc_kernel<<<grid, block, 0, stream>>>(in, emb, out, n, lp);
}

// Round 4
// 761.220 us; speedup vs baseline: 1.1864x; 1.1864x over previous
//
#include <hip/hip_runtime.h>
#include <hip/hip_cooperative_groups.h>
#include <math.h>

namespace cg = cooperative_groups;

#define NLVL 16
#define MAXP (1u << 19)
#define TPB 256
#define NBLK 2048  // 8 blocks/CU x 256 CU -> all co-resident (wave cap 32/CU)

typedef float f32x4 __attribute__((ext_vector_type(4)));

struct LP {
    float        scale[NLVL];
    unsigned int res[NLVL];
    unsigned int hsize[NLVL];
    unsigned int offset[NLVL];
    unsigned int hashed[NLVL];
};

__device__ __forceinline__ void level_point(
    float x, float y, float z, float s, unsigned int r, unsigned int hs,
    unsigned int off, bool hashed, const float* __restrict__ emb,
    float& o0, float& o1)
{
    const float px = x * s, py = y * s, pz = z * s;
    const float gx = floorf(px), gy = floorf(py), gz = floorf(pz);
    const float wx = px - gx, wy = py - gy, wz = pz - gz;
    const unsigned int bx = (unsigned int)(int)gx;
    const unsigned int by = (unsigned int)(int)gy;
    const unsigned int bz = (unsigned int)(int)gz;
    // per-axis index terms: hash (uint32 wrap) or dense linear
    unsigned int ty0, ty1, tz0, tz1;
    if (hashed) {
        ty0 = by * 2654435761u; ty1 = ty0 + 2654435761u;
        tz0 = bz * 805459861u;  tz1 = tz0 + 805459861u;
    } else {
        ty0 = by * r;           ty1 = ty0 + r;
        tz0 = bz * r * r;       tz1 = tz0 + r * r;
    }
    float a0 = 0.0f, a1 = 0.0f;
    #pragma unroll
    for (int c = 0; c < 8; ++c) {
        const unsigned int dx = c & 1u, dy = (c >> 1) & 1u, dz = (c >> 2) & 1u;
        const unsigned int ix = bx + dx;
        unsigned int idx;
        if (hashed) {
            idx = (ix ^ (dy ? ty1 : ty0) ^ (dz ? tz1 : tz0)) & (hs - 1u);
        } else {
            // idx < 2*hs provably -> one conditional subtract == `% hsize`
            idx = ix + (dy ? ty1 : ty0) + (dz ? tz1 : tz0);
            if (idx >= hs) idx -= hs;
        }
        const float2 f = *(const float2*)(emb + (size_t)(off + idx) * 2u);
        const float w = (dx ? wx : 1.0f - wx) *
                        (dy ? wy : 1.0f - wy) *
                        (dz ? wz : 1.0f - wz);
        a0 = fmaf(w, f.x, a0);
        a1 = fmaf(w, f.y, a1);
    }
    o0 = a0; o1 = a1;
}

// Cooperative, level-phased: the whole GPU processes one hashed level at a
// time (grid.sync between levels 4..15), so each XCD's 4 MiB L2 holds the
// active level's exactly-4-MiB table slice -> gathers become L2 hits.
// One thread owns 2 points and all 16 levels; full-128B coalesced output.
__global__ __launch_bounds__(TPB, 8) void grid_enc_coop(
    const float* __restrict__ in, const float* __restrict__ emb,
    float* __restrict__ out, int n, int TT, LP lp)
{
    cg::grid_group gg = cg::this_grid();

    const int t  = blockIdx.x * TPB + threadIdx.x;
    const int p0 = t, p1 = t + TT;
    const bool v0 = p0 < n, v1 = p1 < n;

    // defaults x=0 -> bx=0 -> all gather indices valid for inactive points
    float x0 = 0.f, y0 = 0.f, z0 = 0.f, x1 = 0.f, y1 = 0.f, z1 = 0.f;
    if (v0) {
        x0 = (in[3 * p0 + 0] + 1.0f) * 0.5f;
        y0 = (in[3 * p0 + 1] + 1.0f) * 0.5f;
        z0 = (in[3 * p0 + 2] + 1.0f) * 0.5f;
    }
    if (v1) {
        x1 = (in[3 * p1 + 0] + 1.0f) * 0.5f;
        y1 = (in[3 * p1 + 1] + 1.0f) * 0.5f;
        z1 = (in[3 * p1 + 2] + 1.0f) * 0.5f;
    }

    float f0[2 * NLVL], f1[2 * NLVL];

    #pragma unroll
    for (int l = 0; l < NLVL; ++l) {
        const bool h = (lp.hashed[l] != 0u);
        level_point(x0, y0, z0, lp.scale[l], lp.res[l], lp.hsize[l],
                    lp.offset[l], h, emb, f0[2 * l], f0[2 * l + 1]);
        level_point(x1, y1, z1, lp.scale[l], lp.res[l], lp.hsize[l],
                    lp.offset[l], h, emb, f1[2 * l], f1[2 * l + 1]);
        // phase boundary between cache-sized hashed levels (and before the
        // first one); ALL threads reach this uniformly (no early returns)
        if (l >= 4 && l < 15) gg.sync();
    }

    if (v0) {
        f32x4* o4 = (f32x4*)(out + (size_t)p0 * 32);
        #pragma unroll
        for (int j = 0; j < 8; ++j) {
            f32x4 v = { f0[4*j+0], f0[4*j+1], f0[4*j+2], f0[4*j+3] };
            __builtin_nontemporal_store(v, o4 + j);  // don't evict table from L2
        }
    }
    if (v1) {
        f32x4* o4 = (f32x4*)(out + (size_t)p1 * 32);
        #pragma unroll
        for (int j = 0; j < 8; ++j) {
            f32x4 v = { f1[4*j+0], f1[4*j+1], f1[4*j+2], f1[4*j+3] };
            __builtin_nontemporal_store(v, o4 + j);
        }
    }
}

// Known-good fallback (round-1 structure): 1 thread / point, all levels.
__global__ __launch_bounds__(256) void grid_enc_fallback(
    const float* __restrict__ in, const float* __restrict__ emb,
    float* __restrict__ out, int n, LP lp)
{
    int i = blockIdx.x * blockDim.x + threadIdx.x;
    if (i >= n) return;
    const float x = (in[3 * i + 0] + 1.0f) * 0.5f;
    const float y = (in[3 * i + 1] + 1.0f) * 0.5f;
    const float z = (in[3 * i + 2] + 1.0f) * 0.5f;
    float fout[2 * NLVL];
    #pragma unroll
    for (int l = 0; l < NLVL; ++l) {
        level_point(x, y, z, lp.scale[l], lp.res[l], lp.hsize[l],
                    lp.offset[l], lp.hashed[l] != 0u, emb,
                    fout[2 * l], fout[2 * l + 1]);
    }
    f32x4* o4 = (f32x4*)(out + (size_t)i * 32);
    #pragma unroll
    for (int j = 0; j < 8; ++j) {
        f32x4 v = { fout[4*j+0], fout[4*j+1], fout[4*j+2], fout[4*j+3] };
        __builtin_nontemporal_store(v, o4 + j);
    }
}

extern "C" void kernel_launch(void* const* d_in, const int* in_sizes, int n_in,
                              void* d_out, int out_size, void* d_ws, size_t ws_size,
                              hipStream_t stream)
{
    const float* in  = (const float*)d_in[0];
    const float* emb = (const float*)d_in[1];
    float* out = (float*)d_out;
    int n = in_sizes[0] / 3;

    // Per-level params, f64 exactly as the Python reference.
    LP lp;
    unsigned int offset = 0;
    const double log2s = log2(1.3819);
    for (int l = 0; l < NLVL; ++l) {
        const double scale = pow(2.0, (double)l * log2s) * 16.0 - 1.0;
        const int res = (int)ceil(scale) + 1;
        const long long r3 = (long long)res * res * res;
        const bool dense = (r3 <= (long long)MAXP);
        long long pil = dense ? r3 : (long long)MAXP;
        pil = (pil + 7) / 8 * 8;
        lp.scale[l]  = (float)scale;
        lp.res[l]    = (unsigned int)res;
        lp.hsize[l]  = (unsigned int)pil;
        lp.offset[l] = offset;
        lp.hashed[l] = dense ? 0u : 1u;
        offset += (unsigned int)pil;
    }

    int occ = 0;
    hipError_t oe = hipOccupancyMaxActiveBlocksPerMultiprocessor(
        &occ, grid_enc_coop, TPB, 0);

    bool launched = false;
    if (oe == hipSuccess && occ >= 8) {
        int TT = NBLK * TPB;  // 524288 threads -> 2 points/thread for n=1M
        void* kargs[] = { (void*)&in, (void*)&emb, (void*)&out,
                          (void*)&n, (void*)&TT, (void*)&lp };
        hipError_t le = hipLaunchCooperativeKernel(
            grid_enc_coop, dim3(NBLK), dim3(TPB), kargs, 0, stream);
        launched = (le == hipSuccess);
    }
    if (!launched) {
        const int grid = (n + 255) / 256;
        grid_enc_fallback<<<grid, 256, 0, stream>>>(in, emb, out, n, lp);
    }
}

// Round 5
// 582.742 us; speedup vs baseline: 1.5498x; 1.3063x over previous
//
#include <hip/hip_runtime.h>
#include <math.h>

#define NLVL 16
#define NDENSE 5
#define NHASH 11
#define MAXP (1u << 19)

typedef float f32x2 __attribute__((ext_vector_type(2)));
typedef float f32x4 __attribute__((ext_vector_type(4)));

struct LP {
    float        scale[NLVL];
    unsigned int res[NLVL];
    unsigned int hsize[NLVL];
    unsigned int offset[NLVL];
    unsigned int hashed[NLVL];
};

__device__ __forceinline__ void dense_level(
    float x, float y, float z, float s, unsigned int r, unsigned int hs,
    unsigned int off, const float* __restrict__ emb, float& o0, float& o1)
{
    const float px = x * s, py = y * s, pz = z * s;
    const float gx = floorf(px), gy = floorf(py), gz = floorf(pz);
    const float wx = px - gx, wy = py - gy, wz = pz - gz;
    const unsigned int bx = (unsigned int)(int)gx;
    const unsigned int by = (unsigned int)(int)gy;
    const unsigned int bz = (unsigned int)(int)gz;
    const unsigned int ty0 = by * r,     ty1 = ty0 + r;
    const unsigned int tz0 = bz * r * r, tz1 = tz0 + r * r;
    float a0 = 0.0f, a1 = 0.0f;
    #pragma unroll
    for (int c = 0; c < 8; ++c) {
        const unsigned int dx = c & 1u, dy = (c >> 1) & 1u, dz = (c >> 2) & 1u;
        // idx < 2*hs provably -> one conditional subtract == `% hsize`
        unsigned int idx = (bx + dx) + (dy ? ty1 : ty0) + (dz ? tz1 : tz0);
        if (idx >= hs) idx -= hs;
        const float2 f = *(const float2*)(emb + (size_t)(off + idx) * 2u);
        const float w = (dx ? wx : 1.0f - wx) *
                        (dy ? wy : 1.0f - wy) *
                        (dz ? wz : 1.0f - wz);
        a0 = fmaf(w, f.x, a0);
        a1 = fmaf(w, f.y, a1);
    }
    o0 = a0; o1 = a1;
}

// One hashed level for all points. The whole chip works this single 4-MiB
// table -> each XCD's 4-MiB L2 caches it entirely; misses ~= compulsory.
// Output slice is level-major [N,2] in ws, coalesced 8-B nt stores.
__global__ __launch_bounds__(256) void hash_level_kernel(
    const float* __restrict__ in, const float* __restrict__ emb,
    f32x2* __restrict__ wsl, int n, float s, unsigned int off)
{
    const int i = blockIdx.x * blockDim.x + threadIdx.x;
    if (i >= n) return;
    const float x = (in[3 * i + 0] + 1.0f) * 0.5f;
    const float y = (in[3 * i + 1] + 1.0f) * 0.5f;
    const float z = (in[3 * i + 2] + 1.0f) * 0.5f;
    const float px = x * s, py = y * s, pz = z * s;
    const float gx = floorf(px), gy = floorf(py), gz = floorf(pz);
    const float wx = px - gx, wy = py - gy, wz = pz - gz;
    const unsigned int bx = (unsigned int)(int)gx;
    const unsigned int by = (unsigned int)(int)gy;
    const unsigned int bz = (unsigned int)(int)gz;
    // tcnn fast_hash terms, uint32 wrap (adds distribute over mod 2^32)
    const unsigned int hy0 = by * 2654435761u, hy1 = hy0 + 2654435761u;
    const unsigned int hz0 = bz * 805459861u,  hz1 = hz0 + 805459861u;
    float a0 = 0.0f, a1 = 0.0f;
    #pragma unroll
    for (int c = 0; c < 8; ++c) {
        const unsigned int dx = c & 1u, dy = (c >> 1) & 1u, dz = (c >> 2) & 1u;
        const unsigned int idx =
            ((bx + dx) ^ (dy ? hy1 : hy0) ^ (dz ? hz1 : hz0)) & (MAXP - 1u);
        const float2 f = *(const float2*)(emb + (size_t)(off + idx) * 2u);
        const float w = (dx ? wx : 1.0f - wx) *
                        (dy ? wy : 1.0f - wy) *
                        (dz ? wz : 1.0f - wz);
        a0 = fmaf(w, f.x, a0);
        a1 = fmaf(w, f.y, a1);
    }
    f32x2 v = { a0, a1 };
    __builtin_nontemporal_store(v, wsl + i);  // keep table resident in L2
}

// Dense levels 0..4 (2.65 MB of tables, L2-resident) + gather the 11 hashed
// slices from ws (coalesced) -> write [N,32] point-major, nt float4 stores.
__global__ __launch_bounds__(256) void assemble_kernel(
    const float* __restrict__ in, const float* __restrict__ emb,
    const f32x2* __restrict__ ws, float* __restrict__ out, int n, LP lp)
{
    const int i = blockIdx.x * blockDim.x + threadIdx.x;
    if (i >= n) return;
    const float x = (in[3 * i + 0] + 1.0f) * 0.5f;
    const float y = (in[3 * i + 1] + 1.0f) * 0.5f;
    const float z = (in[3 * i + 2] + 1.0f) * 0.5f;

    float fout[2 * NLVL];
    #pragma unroll
    for (int l = 0; l < NDENSE; ++l)   // constant indices after unroll
        dense_level(x, y, z, lp.scale[l], lp.res[l], lp.hsize[l],
                    lp.offset[l], emb, fout[2 * l], fout[2 * l + 1]);

    #pragma unroll
    for (int l = NDENSE; l < NLVL; ++l) {
        const f32x2 v = __builtin_nontemporal_load(
            ws + (size_t)(l - NDENSE) * (size_t)n + i);
        fout[2 * l + 0] = v.x;
        fout[2 * l + 1] = v.y;
    }

    f32x4* o4 = (f32x4*)(out + (size_t)i * 32);
    #pragma unroll
    for (int j = 0; j < 8; ++j) {
        f32x4 v = { fout[4*j+0], fout[4*j+1], fout[4*j+2], fout[4*j+3] };
        __builtin_nontemporal_store(v, o4 + j);
    }
}

// Known-good fallback (round-1 structure, 675 us) if ws is too small.
__global__ __launch_bounds__(256) void grid_enc_fallback(
    const float* __restrict__ in, const float* __restrict__ emb,
    float* __restrict__ out, int n, LP lp)
{
    const int i = blockIdx.x * blockDim.x + threadIdx.x;
    if (i >= n) return;
    const float x = (in[3 * i + 0] + 1.0f) * 0.5f;
    const float y = (in[3 * i + 1] + 1.0f) * 0.5f;
    const float z = (in[3 * i + 2] + 1.0f) * 0.5f;
    float fout[2 * NLVL];
    #pragma unroll
    for (int l = 0; l < NLVL; ++l) {
        const float s  = lp.scale[l];
        const float px = x * s, py = y * s, pz = z * s;
        const float gx = floorf(px), gy = floorf(py), gz = floorf(pz);
        const float wx = px - gx, wy = py - gy, wz = pz - gz;
        const unsigned int bx = (unsigned int)(int)gx;
        const unsigned int by = (unsigned int)(int)gy;
        const unsigned int bz = (unsigned int)(int)gz;
        const unsigned int r = lp.res[l], hs = lp.hsize[l], off = lp.offset[l];
        const bool hashed = (lp.hashed[l] != 0u);
        float a0 = 0.0f, a1 = 0.0f;
        #pragma unroll
        for (int c = 0; c < 8; ++c) {
            const unsigned int dx = c & 1u, dy = (c >> 1) & 1u, dz = (c >> 2) & 1u;
            const unsigned int ix = bx + dx, iy = by + dy, iz = bz + dz;
            unsigned int idx;
            if (hashed) {
                idx = (ix ^ (iy * 2654435761u) ^ (iz * 805459861u)) & (hs - 1u);
            } else {
                idx = ix + iy * r + iz * r * r;
                if (idx >= hs) idx -= hs;
            }
            const float2 f = *(const float2*)(emb + (size_t)(off + idx) * 2u);
            const float w = (dx ? wx : 1.0f - wx) *
                            (dy ? wy : 1.0f - wy) *
                            (dz ? wz : 1.0f - wz);
            a0 = fmaf(w, f.x, a0);
            a1 = fmaf(w, f.y, a1);
        }
        fout[2 * l + 0] = a0;
        fout[2 * l + 1] = a1;
    }
    f32x4* o4 = (f32x4*)(out + (size_t)i * 32);
    #pragma unroll
    for (int j = 0; j < 8; ++j) {
        f32x4 v = { fout[4*j+0], fout[4*j+1], fout[4*j+2], fout[4*j+3] };
        __builtin_nontemporal_store(v, o4 + j);
    }
}

extern "C" void kernel_launch(void* const* d_in, const int* in_sizes, int n_in,
                              void* d_out, int out_size, void* d_ws, size_t ws_size,
                              hipStream_t stream)
{
    const float* in  = (const float*)d_in[0];
    const float* emb = (const float*)d_in[1];
    float* out = (float*)d_out;
    const int n = in_sizes[0] / 3;

    // Per-level params, f64 exactly as the Python reference.
    LP lp;
    unsigned int offset = 0;
    const double log2s = log2(1.3819);
    for (int l = 0; l < NLVL; ++l) {
        const double scale = pow(2.0, (double)l * log2s) * 16.0 - 1.0;
        const int res = (int)ceil(scale) + 1;
        const long long r3 = (long long)res * res * res;
        const bool dense = (r3 <= (long long)MAXP);
        long long pil = dense ? r3 : (long long)MAXP;
        pil = (pil + 7) / 8 * 8;
        lp.scale[l]  = (float)scale;
        lp.res[l]    = (unsigned int)res;
        lp.hsize[l]  = (unsigned int)pil;
        lp.offset[l] = offset;
        lp.hashed[l] = dense ? 0u : 1u;
        offset += (unsigned int)pil;
    }

    const int block = 256;
    const int grid = (n + block - 1) / block;
    const size_t ws_need = (size_t)NHASH * (size_t)n * sizeof(f32x2);

    if (ws_size >= ws_need) {
        f32x2* ws = (f32x2*)d_ws;
        // one kernel per hashed level: stream-ordered launches are the
        // global barrier that keeps exactly one 4-MiB table hot per L2
        for (int l = NDENSE; l < NLVL; ++l) {
            hash_level_kernel<<<grid, block, 0, stream>>>(
                in, emb, ws + (size_t)(l - NDENSE) * (size_t)n,
                n, lp.scale[l], lp.offset[l]);
        }
        assemble_kernel<<<grid, block, 0, stream>>>(in, emb, ws, out, n, lp);
    } else {
        grid_enc_fallback<<<grid, block, 0, stream>>>(in, emb, out, n, lp);
    }
}

// Round 6
// 487.741 us; speedup vs baseline: 1.8517x; 1.1948x over previous
//
#include <hip/hip_runtime.h>
#include <math.h>

#define NLVL 16
#define NDENSE 5
#define NHASH 11
#define MAXP (1u << 19)

typedef float f32x2 __attribute__((ext_vector_type(2)));
typedef float f32x4 __attribute__((ext_vector_type(4)));

struct LP {
    float        scale[NLVL];
    unsigned int res[NLVL];
    unsigned int hsize[NLVL];
    unsigned int offset[NLVL];
    unsigned int hashed[NLVL];
};

__device__ __forceinline__ void dense_level(
    float x, float y, float z, float s, unsigned int r, unsigned int hs,
    unsigned int off, const float* __restrict__ emb, float& o0, float& o1)
{
    const float px = x * s, py = y * s, pz = z * s;
    const float gx = floorf(px), gy = floorf(py), gz = floorf(pz);
    const float wx = px - gx, wy = py - gy, wz = pz - gz;
    const unsigned int bx = (unsigned int)(int)gx;
    const unsigned int by = (unsigned int)(int)gy;
    const unsigned int bz = (unsigned int)(int)gz;
    const unsigned int ty0 = by * r,     ty1 = ty0 + r;
    const unsigned int tz0 = bz * r * r, tz1 = tz0 + r * r;
    float a0 = 0.0f, a1 = 0.0f;
    #pragma unroll
    for (int c = 0; c < 8; ++c) {
        const unsigned int dx = c & 1u, dy = (c >> 1) & 1u, dz = (c >> 2) & 1u;
        // idx < 2*hs provably -> one conditional subtract == `% hsize`
        unsigned int idx = (bx + dx) + (dy ? ty1 : ty0) + (dz ? tz1 : tz0);
        if (idx >= hs) idx -= hs;
        const float2 f = *(const float2*)(emb + (size_t)(off + idx) * 2u);
        const float w = (dx ? wx : 1.0f - wx) *
                        (dy ? wy : 1.0f - wy) *
                        (dz ? wz : 1.0f - wz);
        a0 = fmaf(w, f.x, a0);
        a1 = fmaf(w, f.y, a1);
    }
    o0 = a0; o1 = a1;
}

// One hashed level for all points. The whole chip works this single 4-MiB
// table -> each XCD's 4-MiB L2 caches it entirely; misses ~= compulsory.
// Output slice is level-major [N,2] in ws: lane-contiguous 8-B nt stores
// (512 B contiguous per wave instruction -> full write-combining, and nt
// keeps the stream from evicting the table).
__global__ __launch_bounds__(256) void hash_level_kernel(
    const float* __restrict__ in, const float* __restrict__ emb,
    f32x2* __restrict__ wsl, int n, float s, unsigned int off)
{
    const int i = blockIdx.x * blockDim.x + threadIdx.x;
    if (i >= n) return;
    const float x = (in[3 * i + 0] + 1.0f) * 0.5f;
    const float y = (in[3 * i + 1] + 1.0f) * 0.5f;
    const float z = (in[3 * i + 2] + 1.0f) * 0.5f;
    const float px = x * s, py = y * s, pz = z * s;
    const float gx = floorf(px), gy = floorf(py), gz = floorf(pz);
    const float wx = px - gx, wy = py - gy, wz = pz - gz;
    const unsigned int bx = (unsigned int)(int)gx;
    const unsigned int by = (unsigned int)(int)gy;
    const unsigned int bz = (unsigned int)(int)gz;
    // tcnn fast_hash terms, uint32 wrap (adds distribute over mod 2^32)
    const unsigned int hy0 = by * 2654435761u, hy1 = hy0 + 2654435761u;
    const unsigned int hz0 = bz * 805459861u,  hz1 = hz0 + 805459861u;
    float a0 = 0.0f, a1 = 0.0f;
    #pragma unroll
    for (int c = 0; c < 8; ++c) {
        const unsigned int dx = c & 1u, dy = (c >> 1) & 1u, dz = (c >> 2) & 1u;
        const unsigned int idx =
            ((bx + dx) ^ (dy ? hy1 : hy0) ^ (dz ? hz1 : hz0)) & (MAXP - 1u);
        const float2 f = *(const float2*)(emb + (size_t)(off + idx) * 2u);
        const float w = (dx ? wx : 1.0f - wx) *
                        (dy ? wy : 1.0f - wy) *
                        (dz ? wz : 1.0f - wz);
        a0 = fmaf(w, f.x, a0);
        a1 = fmaf(w, f.y, a1);
    }
    f32x2 v = { a0, a1 };
    __builtin_nontemporal_store(v, wsl + i);
}

// Dense levels 0..4 (2.65 MB of tables, L3-resident) + gather the 11 hashed
// slices from ws (coalesced nt loads) -> write [N,32] point-major.
// REGULAR cached stores for out: at 128-B-per-lane stride, nt stores flushed
// 16-B fragments as full 64-B HBM lines (4x write amplification, measured
// 502 MB for a 128 MB output in round 5); regular stores merge in L2
// (round 1: same pattern, WRITE_SIZE 125 MB).
__global__ __launch_bounds__(256) void assemble_kernel(
    const float* __restrict__ in, const float* __restrict__ emb,
    const f32x2* __restrict__ ws, float* __restrict__ out, int n, LP lp)
{
    const int i = blockIdx.x * blockDim.x + threadIdx.x;
    if (i >= n) return;
    const float x = (in[3 * i + 0] + 1.0f) * 0.5f;
    const float y = (in[3 * i + 1] + 1.0f) * 0.5f;
    const float z = (in[3 * i + 2] + 1.0f) * 0.5f;

    float fout[2 * NLVL];
    #pragma unroll
    for (int l = 0; l < NDENSE; ++l)   // constant indices after unroll
        dense_level(x, y, z, lp.scale[l], lp.res[l], lp.hsize[l],
                    lp.offset[l], emb, fout[2 * l], fout[2 * l + 1]);

    #pragma unroll
    for (int l = NDENSE; l < NLVL; ++l) {
        const f32x2 v = __builtin_nontemporal_load(
            ws + (size_t)(l - NDENSE) * (size_t)n + i);
        fout[2 * l + 0] = v.x;
        fout[2 * l + 1] = v.y;
    }

    float4* o4 = (float4*)(out + (size_t)i * 32);
    #pragma unroll
    for (int j = 0; j < 8; ++j)
        o4[j] = make_float4(fout[4*j+0], fout[4*j+1],
                            fout[4*j+2], fout[4*j+3]);
}

// Known-good fallback (round-1 structure, 675 us) if ws is too small.
__global__ __launch_bounds__(256) void grid_enc_fallback(
    const float* __restrict__ in, const float* __restrict__ emb,
    float* __restrict__ out, int n, LP lp)
{
    const int i = blockIdx.x * blockDim.x + threadIdx.x;
    if (i >= n) return;
    const float x = (in[3 * i + 0] + 1.0f) * 0.5f;
    const float y = (in[3 * i + 1] + 1.0f) * 0.5f;
    const float z = (in[3 * i + 2] + 1.0f) * 0.5f;
    float fout[2 * NLVL];
    #pragma unroll
    for (int l = 0; l < NLVL; ++l) {
        const float s  = lp.scale[l];
        const float px = x * s, py = y * s, pz = z * s;
        const float gx = floorf(px), gy = floorf(py), gz = floorf(pz);
        const float wx = px - gx, wy = py - gy, wz = pz - gz;
        const unsigned int bx = (unsigned int)(int)gx;
        const unsigned int by = (unsigned int)(int)gy;
        const unsigned int bz = (unsigned int)(int)gz;
        const unsigned int r = lp.res[l], hs = lp.hsize[l], off = lp.offset[l];
        const bool hashed = (lp.hashed[l] != 0u);
        float a0 = 0.0f, a1 = 0.0f;
        #pragma unroll
        for (int c = 0; c < 8; ++c) {
            const unsigned int dx = c & 1u, dy = (c >> 1) & 1u, dz = (c >> 2) & 1u;
            const unsigned int ix = bx + dx, iy = by + dy, iz = bz + dz;
            unsigned int idx;
            if (hashed) {
                idx = (ix ^ (iy * 2654435761u) ^ (iz * 805459861u)) & (hs - 1u);
            } else {
                idx = ix + iy * r + iz * r * r;
                if (idx >= hs) idx -= hs;
            }
            const float2 f = *(const float2*)(emb + (size_t)(off + idx) * 2u);
            const float w = (dx ? wx : 1.0f - wx) *
                            (dy ? wy : 1.0f - wy) *
                            (dz ? wz : 1.0f - wz);
            a0 = fmaf(w, f.x, a0);
            a1 = fmaf(w, f.y, a1);
        }
        fout[2 * l + 0] = a0;
        fout[2 * l + 1] = a1;
    }
    float4* o4 = (float4*)(out + (size_t)i * 32);
    #pragma unroll
    for (int j = 0; j < 8; ++j)
        o4[j] = make_float4(fout[4*j+0], fout[4*j+1],
                            fout[4*j+2], fout[4*j+3]);
}

extern "C" void kernel_launch(void* const* d_in, const int* in_sizes, int n_in,
                              void* d_out, int out_size, void* d_ws, size_t ws_size,
                              hipStream_t stream)
{
    const float* in  = (const float*)d_in[0];
    const float* emb = (const float*)d_in[1];
    float* out = (float*)d_out;
    const int n = in_sizes[0] / 3;

    // Per-level params, f64 exactly as the Python reference.
    LP lp;
    unsigned int offset = 0;
    const double log2s = log2(1.3819);
    for (int l = 0; l < NLVL; ++l) {
        const double scale = pow(2.0, (double)l * log2s) * 16.0 - 1.0;
        const int res = (int)ceil(scale) + 1;
        const long long r3 = (long long)res * res * res;
        const bool dense = (r3 <= (long long)MAXP);
        long long pil = dense ? r3 : (long long)MAXP;
        pil = (pil + 7) / 8 * 8;
        lp.scale[l]  = (float)scale;
        lp.res[l]    = (unsigned int)res;
        lp.hsize[l]  = (unsigned int)pil;
        lp.offset[l] = offset;
        lp.hashed[l] = dense ? 0u : 1u;
        offset += (unsigned int)pil;
    }

    const int block = 256;
    const int grid = (n + block - 1) / block;
    const size_t ws_need = (size_t)NHASH * (size_t)n * sizeof(f32x2);

    if (ws_size >= ws_need) {
        f32x2* ws = (f32x2*)d_ws;
        // one kernel per hashed level: stream-ordered launches are the
        // global barrier that keeps exactly one 4-MiB table hot per L2
        for (int l = NDENSE; l < NLVL; ++l) {
            hash_level_kernel<<<grid, block, 0, stream>>>(
                in, emb, ws + (size_t)(l - NDENSE) * (size_t)n,
                n, lp.scale[l], lp.offset[l]);
        }
        assemble_kernel<<<grid, block, 0, stream>>>(in, emb, ws, out, n, lp);
    } else {
        grid_enc_fallback<<<grid, block, 0, stream>>>(in, emb, out, n, lp);
    }
}

// Round 7
// 431.343 us; speedup vs baseline: 2.0938x; 1.1307x over previous
//
#include <hip/hip_runtime.h>
#include <math.h>

#define NLVL 16
#define NDENSE 5
#define NHASH 11
#define MAXP (1u << 19)
#define HMASK (MAXP - 1u)

typedef float f32x2 __attribute__((ext_vector_type(2)));
typedef float f32x4 __attribute__((ext_vector_type(4)));
// 8-B-aligned 16-B vector: dense corner pairs are only 8-B aligned; gfx950
// global loads support dword alignment, so this still emits one dwordx4.
typedef float f32x4u __attribute__((ext_vector_type(4), aligned(8)));

struct LP {
    float        scale[NLVL];
    unsigned int res[NLVL];
    unsigned int hsize[NLVL];
    unsigned int offset[NLVL];
    unsigned int hashed[NLVL];
};

// Dense level with x-paired corner loads: corners (dx=0,dx=1) sit at idx and
// idx+1 -> ONE 16-B load fetches both (gathers 8 -> 4 per level).
// No index wrap: inputs in [-1,1) -> bx <= res-2 -> idx+1 <= r^3-1 < hsize.
__device__ __forceinline__ void dense_level(
    float x, float y, float z, float s, unsigned int r,
    unsigned int off, const float* __restrict__ emb, float& o0, float& o1)
{
    const float px = x * s, py = y * s, pz = z * s;
    const float gx = floorf(px), gy = floorf(py), gz = floorf(pz);
    const float wx = px - gx, wy = py - gy, wz = pz - gz;
    const float ux = 1.0f - wx, uy = 1.0f - wy, uz = 1.0f - wz;
    const unsigned int bx = (unsigned int)(int)gx;
    const unsigned int by = (unsigned int)(int)gy;
    const unsigned int bz = (unsigned int)(int)gz;
    const unsigned int ty0 = by * r,     ty1 = ty0 + r;
    const unsigned int tz0 = bz * r * r, tz1 = tz0 + r * r;
    float a0 = 0.0f, a1 = 0.0f;
    #pragma unroll
    for (int c = 0; c < 4; ++c) {
        const unsigned int dy = c & 1u, dz = (c >> 1) & 1u;
        const unsigned int idx = bx + (dy ? ty1 : ty0) + (dz ? tz1 : tz0);
        const f32x4u v = *(const f32x4u*)(emb + (size_t)(off + idx) * 2u);
        const float wyz = (dy ? wy : uy) * (dz ? wz : uz);
        a0 = fmaf(wyz * ux, v.x, a0);
        a1 = fmaf(wyz * ux, v.y, a1);
        a0 = fmaf(wyz * wx, v.z, a0);
        a1 = fmaf(wyz * wx, v.w, a1);
    }
    o0 = a0; o1 = a1;
}

// One hashed level for all points (whole chip on one 4-MiB table -> each
// XCD L2 caches it; phasing via stream-ordered launches).
// x-pairing: PRIME0==1, so when bx is even idx(dx=1)=idx(dx=0)^1 -> the two
// corners are an aligned 16-B pair {base,base+1} -> one dwordx4 + selects.
// bx odd keeps two 8-B gathers. Avg 6 lane-transactions/point vs 8.
__global__ __launch_bounds__(256) void hash_level_kernel(
    const float* __restrict__ in, const float* __restrict__ emb,
    f32x2* __restrict__ wsl, int n, float s, unsigned int off)
{
    const int i = blockIdx.x * blockDim.x + threadIdx.x;
    if (i >= n) return;
    const float x = (in[3 * i + 0] + 1.0f) * 0.5f;
    const float y = (in[3 * i + 1] + 1.0f) * 0.5f;
    const float z = (in[3 * i + 2] + 1.0f) * 0.5f;
    const float px = x * s, py = y * s, pz = z * s;
    const float gx = floorf(px), gy = floorf(py), gz = floorf(pz);
    const float wx = px - gx, wy = py - gy, wz = pz - gz;
    const float ux = 1.0f - wx, uy = 1.0f - wy, uz = 1.0f - wz;
    const unsigned int bx = (unsigned int)(int)gx;
    const unsigned int by = (unsigned int)(int)gy;
    const unsigned int bz = (unsigned int)(int)gz;
    // tcnn fast_hash terms, uint32 wrap (adds distribute over mod 2^32)
    const unsigned int hy0 = by * 2654435761u, hy1 = hy0 + 2654435761u;
    const unsigned int hz0 = bz * 805459861u,  hz1 = hz0 + 805459861u;

    float a0 = 0.0f, a1 = 0.0f;
    if (!(bx & 1u)) {
        #pragma unroll
        for (int c = 0; c < 4; ++c) {
            const unsigned int dy = c & 1u, dz = (c >> 1) & 1u;
            const unsigned int hyz = (dy ? hy1 : hy0) ^ (dz ? hz1 : hz0);
            const unsigned int idx0 = (bx ^ hyz) & HMASK;
            const unsigned int base = idx0 & ~1u;          // 16-B aligned pair
            const f32x4 v = *(const f32x4*)(emb + (size_t)(off + base) * 2u);
            const bool hi = (idx0 & 1u) != 0u;             // which slot is dx=0
            const float f0x = hi ? v.z : v.x, f0y = hi ? v.w : v.y;
            const float f1x = hi ? v.x : v.z, f1y = hi ? v.y : v.w;
            const float wyz = (dy ? wy : uy) * (dz ? wz : uz);
            a0 = fmaf(wyz * ux, f0x, a0);
            a1 = fmaf(wyz * ux, f0y, a1);
            a0 = fmaf(wyz * wx, f1x, a0);
            a1 = fmaf(wyz * wx, f1y, a1);
        }
    } else {
        #pragma unroll
        for (int c = 0; c < 8; ++c) {
            const unsigned int dx = c & 1u, dy = (c >> 1) & 1u, dz = (c >> 2) & 1u;
            const unsigned int idx =
                ((bx + dx) ^ (dy ? hy1 : hy0) ^ (dz ? hz1 : hz0)) & HMASK;
            const float2 f = *(const float2*)(emb + (size_t)(off + idx) * 2u);
            const float w = (dx ? wx : ux) * (dy ? wy : uy) * (dz ? wz : uz);
            a0 = fmaf(w, f.x, a0);
            a1 = fmaf(w, f.y, a1);
        }
    }
    f32x2 v = { a0, a1 };
    __builtin_nontemporal_store(v, wsl + i);  // keep table resident in L2
}

// Dense levels 0..4 (2.65 MB, cache-resident, x-paired gathers) + gather the
// 11 hashed slices from ws (coalesced nt loads) -> [N,32] point-major via
// regular cached float4 stores (nt here caused 4x write amplification, r5).
__global__ __launch_bounds__(256) void assemble_kernel(
    const float* __restrict__ in, const float* __restrict__ emb,
    const f32x2* __restrict__ ws, float* __restrict__ out, int n, LP lp)
{
    const int i = blockIdx.x * blockDim.x + threadIdx.x;
    if (i >= n) return;
    const float x = (in[3 * i + 0] + 1.0f) * 0.5f;
    const float y = (in[3 * i + 1] + 1.0f) * 0.5f;
    const float z = (in[3 * i + 2] + 1.0f) * 0.5f;

    float fout[2 * NLVL];
    #pragma unroll
    for (int l = 0; l < NDENSE; ++l)   // constant indices after unroll
        dense_level(x, y, z, lp.scale[l], lp.res[l],
                    lp.offset[l], emb, fout[2 * l], fout[2 * l + 1]);

    #pragma unroll
    for (int l = NDENSE; l < NLVL; ++l) {
        const f32x2 v = __builtin_nontemporal_load(
            ws + (size_t)(l - NDENSE) * (size_t)n + i);
        fout[2 * l + 0] = v.x;
        fout[2 * l + 1] = v.y;
    }

    float4* o4 = (float4*)(out + (size_t)i * 32);
    #pragma unroll
    for (int j = 0; j < 8; ++j)
        o4[j] = make_float4(fout[4*j+0], fout[4*j+1],
                            fout[4*j+2], fout[4*j+3]);
}

// Known-good fallback (round-1 structure) if ws is too small.
__global__ __launch_bounds__(256) void grid_enc_fallback(
    const float* __restrict__ in, const float* __restrict__ emb,
    float* __restrict__ out, int n, LP lp)
{
    const int i = blockIdx.x * blockDim.x + threadIdx.x;
    if (i >= n) return;
    const float x = (in[3 * i + 0] + 1.0f) * 0.5f;
    const float y = (in[3 * i + 1] + 1.0f) * 0.5f;
    const float z = (in[3 * i + 2] + 1.0f) * 0.5f;
    float fout[2 * NLVL];
    #pragma unroll
    for (int l = 0; l < NLVL; ++l) {
        const float s  = lp.scale[l];
        const float px = x * s, py = y * s, pz = z * s;
        const float gx = floorf(px), gy = floorf(py), gz = floorf(pz);
        const float wx = px - gx, wy = py - gy, wz = pz - gz;
        const unsigned int bx = (unsigned int)(int)gx;
        const unsigned int by = (unsigned int)(int)gy;
        const unsigned int bz = (unsigned int)(int)gz;
        const unsigned int r = lp.res[l], hs = lp.hsize[l], off = lp.offset[l];
        const bool hashed = (lp.hashed[l] != 0u);
        float a0 = 0.0f, a1 = 0.0f;
        #pragma unroll
        for (int c = 0; c < 8; ++c) {
            const unsigned int dx = c & 1u, dy = (c >> 1) & 1u, dz = (c >> 2) & 1u;
            const unsigned int ix = bx + dx, iy = by + dy, iz = bz + dz;
            unsigned int idx;
            if (hashed) {
                idx = (ix ^ (iy * 2654435761u) ^ (iz * 805459861u)) & (hs - 1u);
            } else {
                idx = ix + iy * r + iz * r * r;
                if (idx >= hs) idx -= hs;
            }
            const float2 f = *(const float2*)(emb + (size_t)(off + idx) * 2u);
            const float w = (dx ? wx : 1.0f - wx) *
                            (dy ? wy : 1.0f - wy) *
                            (dz ? wz : 1.0f - wz);
            a0 = fmaf(w, f.x, a0);
            a1 = fmaf(w, f.y, a1);
        }
        fout[2 * l + 0] = a0;
        fout[2 * l + 1] = a1;
    }
    float4* o4 = (float4*)(out + (size_t)i * 32);
    #pragma unroll
    for (int j = 0; j < 8; ++j)
        o4[j] = make_float4(fout[4*j+0], fout[4*j+1],
                            fout[4*j+2], fout[4*j+3]);
}

extern "C" void kernel_launch(void* const* d_in, const int* in_sizes, int n_in,
                              void* d_out, int out_size, void* d_ws, size_t ws_size,
                              hipStream_t stream)
{
    const float* in  = (const float*)d_in[0];
    const float* emb = (const float*)d_in[1];
    float* out = (float*)d_out;
    const int n = in_sizes[0] / 3;

    // Per-level params, f64 exactly as the Python reference.
    LP lp;
    unsigned int offset = 0;
    const double log2s = log2(1.3819);
    for (int l = 0; l < NLVL; ++l) {
        const double scale = pow(2.0, (double)l * log2s) * 16.0 - 1.0;
        const int res = (int)ceil(scale) + 1;
        const long long r3 = (long long)res * res * res;
        const bool dense = (r3 <= (long long)MAXP);
        long long pil = dense ? r3 : (long long)MAXP;
        pil = (pil + 7) / 8 * 8;
        lp.scale[l]  = (float)scale;
        lp.res[l]    = (unsigned int)res;
        lp.hsize[l]  = (unsigned int)pil;
        lp.offset[l] = offset;
        lp.hashed[l] = dense ? 0u : 1u;
        offset += (unsigned int)pil;
    }

    const int block = 256;
    const int grid = (n + block - 1) / block;
    const size_t ws_need = (size_t)NHASH * (size_t)n * sizeof(f32x2);

    if (ws_size >= ws_need) {
        f32x2* ws = (f32x2*)d_ws;
        // one kernel per hashed level: stream-ordered launches are the
        // global barrier that keeps exactly one 4-MiB table hot per L2
        for (int l = NDENSE; l < NLVL; ++l) {
            hash_level_kernel<<<grid, block, 0, stream>>>(
                in, emb, ws + (size_t)(l - NDENSE) * (size_t)n,
                n, lp.scale[l], lp.offset[l]);
        }
        assemble_kernel<<<grid, block, 0, stream>>>(in, emb, ws, out, n, lp);
    } else {
        grid_enc_fallback<<<grid, block, 0, stream>>>(in, emb, out, n, lp);
    }
}

// Round 8
// 395.674 us; speedup vs baseline: 2.2825x; 1.0901x over previous
//
#include <hip/hip_runtime.h>
#include <math.h>

#define NLVL 16
#define NDENSE 5
#define NHASH 11
#define MAXP (1u << 19)
#define HMASK (MAXP - 1u)
#define NXCD 8
#define PPB 512   // points per task-block (256 threads x 2 points)

typedef float f32x2 __attribute__((ext_vector_type(2)));
typedef float f32x4 __attribute__((ext_vector_type(4)));
typedef float f32x4u __attribute__((ext_vector_type(4), aligned(8)));

struct LP {
    float        scale[NLVL];
    unsigned int res[NLVL];
    unsigned int hsize[NLVL];
    unsigned int offset[NLVL];
    unsigned int hashed[NLVL];
};

struct LPH {                 // hashed levels only (l = 5..15)
    float        scale[NHASH];
    unsigned int off[NHASH];
};

// One hashed-level evaluation for one point; even-bx x-pairing (one 16-B
// load covers both x-corners; they share a 64-B line either way).
__device__ __forceinline__ void hash_point(
    float x, float y, float z, float s, unsigned int off,
    const float* __restrict__ emb, float& o0, float& o1)
{
    const float px = x * s, py = y * s, pz = z * s;
    const float gx = floorf(px), gy = floorf(py), gz = floorf(pz);
    const float wx = px - gx, wy = py - gy, wz = pz - gz;
    const float ux = 1.0f - wx, uy = 1.0f - wy, uz = 1.0f - wz;
    const unsigned int bx = (unsigned int)(int)gx;
    const unsigned int by = (unsigned int)(int)gy;
    const unsigned int bz = (unsigned int)(int)gz;
    // tcnn fast_hash terms, uint32 wrap (adds distribute over mod 2^32)
    const unsigned int hy0 = by * 2654435761u, hy1 = hy0 + 2654435761u;
    const unsigned int hz0 = bz * 805459861u,  hz1 = hz0 + 805459861u;
    float a0 = 0.0f, a1 = 0.0f;
    if (!(bx & 1u)) {
        #pragma unroll
        for (int c = 0; c < 4; ++c) {
            const unsigned int dy = c & 1u, dz = (c >> 1) & 1u;
            const unsigned int hyz = (dy ? hy1 : hy0) ^ (dz ? hz1 : hz0);
            const unsigned int idx0 = (bx ^ hyz) & HMASK;
            const unsigned int base = idx0 & ~1u;
            const f32x4 v = *(const f32x4*)(emb + (size_t)(off + base) * 2u);
            const bool hi = (idx0 & 1u) != 0u;
            const float f0x = hi ? v.z : v.x, f0y = hi ? v.w : v.y;
            const float f1x = hi ? v.x : v.z, f1y = hi ? v.y : v.w;
            const float wyz = (dy ? wy : uy) * (dz ? wz : uz);
            a0 = fmaf(wyz * ux, f0x, a0);
            a1 = fmaf(wyz * ux, f0y, a1);
            a0 = fmaf(wyz * wx, f1x, a0);
            a1 = fmaf(wyz * wx, f1y, a1);
        }
    } else {
        #pragma unroll
        for (int c = 0; c < 8; ++c) {
            const unsigned int dx = c & 1u, dy = (c >> 1) & 1u, dz = (c >> 2) & 1u;
            const unsigned int idx =
                ((bx + dx) ^ (dy ? hy1 : hy0) ^ (dz ? hz1 : hz0)) & HMASK;
            const float2 f = *(const float2*)(emb + (size_t)(off + idx) * 2u);
            const float w = (dx ? wx : ux) * (dy ? wy : uy) * (dz ? wz : uz);
            a0 = fmaf(w, f.x, a0);
            a1 = fmaf(w, f.y, a1);
        }
    }
    o0 = a0; o1 = a1;
}

// ALL hashed levels in ONE kernel, XCD-serpentine schedule:
// task = (level, chunk-of-512-points). Blocks land on XCD (blockIdx % 8)
// (round-robin dispatch, learn_hip m09/m157), and block b executes task
// tid = (b%8)*T + b/8 -> each XCD gets a CONTIGUOUS task range, i.e. it
// sweeps levels sequentially (<=3 level switches) while its 4-MiB L2 holds
// the active level's 4-MiB table. Same phasing as 11 kernels, zero
// inter-kernel drain bubbles. 2 points/thread for 2x MLP.
__global__ __launch_bounds__(256) void hash_mega_kernel(
    const float* __restrict__ in, const float* __restrict__ emb,
    f32x2* __restrict__ ws, int n, int chunks, int T, int ntask, LPH lph)
{
    const int b   = blockIdx.x;
    const int tid = (b & (NXCD - 1)) * T + (b >> 3);
    if (tid >= ntask) return;
    const int lvl   = tid / chunks;            // uniform scalar div, 0..10
    const int chunk = tid - lvl * chunks;

    const float        s   = lph.scale[lvl];   // uniform index -> s_load
    const unsigned int off = lph.off[lvl];
    f32x2* __restrict__ wsl = ws + (size_t)lvl * (size_t)n;

    const int i0 = chunk * PPB + (int)threadIdx.x;
    const int i1 = i0 + 256;

    // point 0
    if (i0 < n) {
        const float x = (in[3 * i0 + 0] + 1.0f) * 0.5f;
        const float y = (in[3 * i0 + 1] + 1.0f) * 0.5f;
        const float z = (in[3 * i0 + 2] + 1.0f) * 0.5f;
        float a0, a1;
        hash_point(x, y, z, s, off, emb, a0, a1);
        f32x2 v = { a0, a1 };
        __builtin_nontemporal_store(v, wsl + i0);
    }
    // point 1
    if (i1 < n) {
        const float x = (in[3 * i1 + 0] + 1.0f) * 0.5f;
        const float y = (in[3 * i1 + 1] + 1.0f) * 0.5f;
        const float z = (in[3 * i1 + 2] + 1.0f) * 0.5f;
        float a0, a1;
        hash_point(x, y, z, s, off, emb, a0, a1);
        f32x2 v = { a0, a1 };
        __builtin_nontemporal_store(v, wsl + i1);
    }
}

// Dense level with x-paired corner loads (one 16-B load per y/z corner pair).
// No wrap: inputs in [-1,1) -> bx <= res-2 -> idx+1 < hsize.
__device__ __forceinline__ void dense_level(
    float x, float y, float z, float s, unsigned int r,
    unsigned int off, const float* __restrict__ emb, float& o0, float& o1)
{
    const float px = x * s, py = y * s, pz = z * s;
    const float gx = floorf(px), gy = floorf(py), gz = floorf(pz);
    const float wx = px - gx, wy = py - gy, wz = pz - gz;
    const float ux = 1.0f - wx, uy = 1.0f - wy, uz = 1.0f - wz;
    const unsigned int bx = (unsigned int)(int)gx;
    const unsigned int by = (unsigned int)(int)gy;
    const unsigned int bz = (unsigned int)(int)gz;
    const unsigned int ty0 = by * r,     ty1 = ty0 + r;
    const unsigned int tz0 = bz * r * r, tz1 = tz0 + r * r;
    float a0 = 0.0f, a1 = 0.0f;
    #pragma unroll
    for (int c = 0; c < 4; ++c) {
        const unsigned int dy = c & 1u, dz = (c >> 1) & 1u;
        const unsigned int idx = bx + (dy ? ty1 : ty0) + (dz ? tz1 : tz0);
        const f32x4u v = *(const f32x4u*)(emb + (size_t)(off + idx) * 2u);
        const float wyz = (dy ? wy : uy) * (dz ? wz : uz);
        a0 = fmaf(wyz * ux, v.x, a0);
        a1 = fmaf(wyz * ux, v.y, a1);
        a0 = fmaf(wyz * wx, v.z, a0);
        a1 = fmaf(wyz * wx, v.w, a1);
    }
    o0 = a0; o1 = a1;
}

// Dense levels 0..4 + gather 11 hashed slices from ws (coalesced, cached:
// last-written slices hit L2) -> [N,32] point-major, regular float4 stores
// (nt here caused 4x write amplification, r5).
__global__ __launch_bounds__(256) void assemble_kernel(
    const float* __restrict__ in, const float* __restrict__ emb,
    const f32x2* __restrict__ ws, float* __restrict__ out, int n, LP lp)
{
    const int i = blockIdx.x * blockDim.x + threadIdx.x;
    if (i >= n) return;
    const float x = (in[3 * i + 0] + 1.0f) * 0.5f;
    const float y = (in[3 * i + 1] + 1.0f) * 0.5f;
    const float z = (in[3 * i + 2] + 1.0f) * 0.5f;

    float fout[2 * NLVL];
    #pragma unroll
    for (int l = 0; l < NDENSE; ++l)
        dense_level(x, y, z, lp.scale[l], lp.res[l],
                    lp.offset[l], emb, fout[2 * l], fout[2 * l + 1]);

    #pragma unroll
    for (int l = NDENSE; l < NLVL; ++l) {
        const f32x2 v = ws[(size_t)(l - NDENSE) * (size_t)n + i];
        fout[2 * l + 0] = v.x;
        fout[2 * l + 1] = v.y;
    }

    float4* o4 = (float4*)(out + (size_t)i * 32);
    #pragma unroll
    for (int j = 0; j < 8; ++j)
        o4[j] = make_float4(fout[4*j+0], fout[4*j+1],
                            fout[4*j+2], fout[4*j+3]);
}

// Known-good fallback (round-1 structure) if ws is too small.
__global__ __launch_bounds__(256) void grid_enc_fallback(
    const float* __restrict__ in, const float* __restrict__ emb,
    float* __restrict__ out, int n, LP lp)
{
    const int i = blockIdx.x * blockDim.x + threadIdx.x;
    if (i >= n) return;
    const float x = (in[3 * i + 0] + 1.0f) * 0.5f;
    const float y = (in[3 * i + 1] + 1.0f) * 0.5f;
    const float z = (in[3 * i + 2] + 1.0f) * 0.5f;
    float fout[2 * NLVL];
    #pragma unroll
    for (int l = 0; l < NLVL; ++l) {
        const float s  = lp.scale[l];
        const float px = x * s, py = y * s, pz = z * s;
        const float gx = floorf(px), gy = floorf(py), gz = floorf(pz);
        const float wx = px - gx, wy = py - gy, wz = pz - gz;
        const unsigned int bx = (unsigned int)(int)gx;
        const unsigned int by = (unsigned int)(int)gy;
        const unsigned int bz = (unsigned int)(int)gz;
        const unsigned int r = lp.res[l], hs = lp.hsize[l], off = lp.offset[l];
        const bool hashed = (lp.hashed[l] != 0u);
        float a0 = 0.0f, a1 = 0.0f;
        #pragma unroll
        for (int c = 0; c < 8; ++c) {
            const unsigned int dx = c & 1u, dy = (c >> 1) & 1u, dz = (c >> 2) & 1u;
            const unsigned int ix = bx + dx, iy = by + dy, iz = bz + dz;
            unsigned int idx;
            if (hashed) {
                idx = (ix ^ (iy * 2654435761u) ^ (iz * 805459861u)) & (hs - 1u);
            } else {
                idx = ix + iy * r + iz * r * r;
                if (idx >= hs) idx -= hs;
            }
            const float2 f = *(const float2*)(emb + (size_t)(off + idx) * 2u);
            const float w = (dx ? wx : 1.0f - wx) *
                            (dy ? wy : 1.0f - wy) *
                            (dz ? wz : 1.0f - wz);
            a0 = fmaf(w, f.x, a0);
            a1 = fmaf(w, f.y, a1);
        }
        fout[2 * l + 0] = a0;
        fout[2 * l + 1] = a1;
    }
    float4* o4 = (float4*)(out + (size_t)i * 32);
    #pragma unroll
    for (int j = 0; j < 8; ++j)
        o4[j] = make_float4(fout[4*j+0], fout[4*j+1],
                            fout[4*j+2], fout[4*j+3]);
}

extern "C" void kernel_launch(void* const* d_in, const int* in_sizes, int n_in,
                              void* d_out, int out_size, void* d_ws, size_t ws_size,
                              hipStream_t stream)
{
    const float* in  = (const float*)d_in[0];
    const float* emb = (const float*)d_in[1];
    float* out = (float*)d_out;
    const int n = in_sizes[0] / 3;

    // Per-level params, f64 exactly as the Python reference.
    LP lp;
    unsigned int offset = 0;
    const double log2s = log2(1.3819);
    for (int l = 0; l < NLVL; ++l) {
        const double scale = pow(2.0, (double)l * log2s) * 16.0 - 1.0;
        const int res = (int)ceil(scale) + 1;
        const long long r3 = (long long)res * res * res;
        const bool dense = (r3 <= (long long)MAXP);
        long long pil = dense ? r3 : (long long)MAXP;
        pil = (pil + 7) / 8 * 8;
        lp.scale[l]  = (float)scale;
        lp.res[l]    = (unsigned int)res;
        lp.hsize[l]  = (unsigned int)pil;
        lp.offset[l] = offset;
        lp.hashed[l] = dense ? 0u : 1u;
        offset += (unsigned int)pil;
    }

    LPH lph;
    for (int h = 0; h < NHASH; ++h) {
        lph.scale[h] = lp.scale[NDENSE + h];
        lph.off[h]   = lp.offset[NDENSE + h];
    }

    const int block = 256;
    const int grid = (n + block - 1) / block;
    const size_t ws_need = (size_t)NHASH * (size_t)n * sizeof(f32x2);

    if (ws_size >= ws_need) {
        f32x2* ws = (f32x2*)d_ws;
        const int chunks = (n + PPB - 1) / PPB;
        const int ntask  = NHASH * chunks;
        const int T      = (ntask + NXCD - 1) / NXCD;
        const int mgrid  = NXCD * T;
        hash_mega_kernel<<<mgrid, block, 0, stream>>>(
            in, emb, ws, n, chunks, T, ntask, lph);
        assemble_kernel<<<grid, block, 0, stream>>>(in, emb, ws, out, n, lp);
    } else {
        grid_enc_fallback<<<grid, block, 0, stream>>>(in, emb, out, n, lp);
    }
}